// Round 2
// 653.310 us; speedup vs baseline: 1.1327x; 1.1327x over previous
//
#include <hip/hip_runtime.h>

#define TLEN  1024
#define HN    64
#define LOG2E 1.4426950408889634f

// clang builtins (__builtin_amdgcn_cvt_pkrtz / fdot2) use __fp16 vectors,
// NOT _Float16 -- R7 failed to compile on exactly that.
typedef __fp16 half2v __attribute__((ext_vector_type(2)));

// One wave (64 lanes) per batch element; 1024 blocks x 64 thr = 1 wave/SIMD
// exactly -> latency-bound, so this version attacks the per-step critical
// path:
//  * h half-exchange via v_permlane32_swap_b32 (VALU, ~8cy) instead of
//    __shfl_down (ds_bpermute, ~120cy) -- the shfl sat directly on the
//    recurrence chain h -> hp -> next-step readlanes.
//    !! The swap's two operands MUST be distinct physical VGPRs: with
//    tied "+v","+v" on the same SSA value the allocator coalesces them
//    and v_permlane32_swap_b32 v,v has ill-defined write-back (R1 failed
//    correctness on exactly that). Fixed: explicit v_mov into an
//    early-clobber ("=&v") output, then swap.
//  * x staged 64 timesteps at a time: ONE coalesced 16B/lane load per 64
//    steps (lane s holds x[t0+s] packed as 2x half2); per step just two
//    v_readlane broadcasts. Kills per-step global load + addressing + the
//    tn clamp; prefetch distance = 64 steps so vmcnt never stalls.
//  * FC epilogue moved out of the inner loop (inner trip = 64 == FC period)
//    -- no per-step (t&63) branch.
//  * 8 gate accumulators (2 per gate, 17-deep chains) + unroll 2 for
//    scheduling slack across the step boundary.
// Weights: lane g owns hidden unit g's four gate rows (torch i,f,g,o) as
// PACKED f16 pairs {w[j], w[j+32]}: 128 half2 = 128 VGPRs. v_dot2_f32_f16 =
// 2 MACs/instr, fp32 accumulate. log2e pre-folded into all weights/biases
// (2*log2e for tanh gates). NO DS ops in the recurrence.

#define FOR16A(X) \
    X(0) X(1) X(2) X(3) X(4) X(5) X(6) X(7) \
    X(8) X(9) X(10) X(11) X(12) X(13) X(14) X(15)
#define FOR16B(X) \
    X(16) X(17) X(18) X(19) X(20) X(21) X(22) X(23) \
    X(24) X(25) X(26) X(27) X(28) X(29) X(30) X(31)
#define FOR32(X) FOR16A(X) FOR16B(X)

__global__ __launch_bounds__(64, 1)
void lstm_dot2(const float* __restrict__ x,      // [B, T, 4]
               const float* __restrict__ W_ih,   // [256, 4]
               const float* __restrict__ W_hh,   // [256, 64]
               const float* __restrict__ b_ih,   // [256]
               const float* __restrict__ b_hh,   // [256]
               const float* __restrict__ W_fc,   // [1, 64]
               const float* __restrict__ b_fc,   // [1]
               float* __restrict__ out)          // [B, T]
{
    const int b = blockIdx.x;
    const int g = threadIdx.x;   // hidden unit 0..63 (also x-stage slot)

    __shared__ float ring[64][65];   // FC partials, stride-65: conflict-free

    const float* wr_i = W_hh + (0 * HN + g) * HN;
    const float* wr_f = W_hh + (1 * HN + g) * HN;
    const float* wr_g = W_hh + (2 * HN + g) * HN;
    const float* wr_o = W_hh + (3 * HN + g) * HN;

    // ---- 128 named half2 weight pairs, pre-scaled, pinned ----
#define DECL(j) half2v pi##j, pf##j, pg##j, po##j;
    FOR32(DECL)
#undef DECL

#define LOADW(j) \
    pi##j = __builtin_amdgcn_cvt_pkrtz(wr_i[j] * LOG2E, wr_i[(j) + 32] * LOG2E); \
    pf##j = __builtin_amdgcn_cvt_pkrtz(wr_f[j] * LOG2E, wr_f[(j) + 32] * LOG2E); \
    pg##j = __builtin_amdgcn_cvt_pkrtz(wr_g[j] * (2.0f * LOG2E), \
                                       wr_g[(j) + 32] * (2.0f * LOG2E)); \
    po##j = __builtin_amdgcn_cvt_pkrtz(wr_o[j] * LOG2E, wr_o[(j) + 32] * LOG2E); \
    asm volatile("" : "+v"(pi##j), "+v"(pf##j), "+v"(pg##j), "+v"(po##j));
    FOR32(LOADW)
#undef LOADW

    // x-weights as f16 pairs (pre-scaled): 2 half2 per gate
    half2v wip0 = __builtin_amdgcn_cvt_pkrtz(W_ih[(0 * HN + g) * 4 + 0] * LOG2E,
                                             W_ih[(0 * HN + g) * 4 + 1] * LOG2E);
    half2v wip1 = __builtin_amdgcn_cvt_pkrtz(W_ih[(0 * HN + g) * 4 + 2] * LOG2E,
                                             W_ih[(0 * HN + g) * 4 + 3] * LOG2E);
    half2v wfp0 = __builtin_amdgcn_cvt_pkrtz(W_ih[(1 * HN + g) * 4 + 0] * LOG2E,
                                             W_ih[(1 * HN + g) * 4 + 1] * LOG2E);
    half2v wfp1 = __builtin_amdgcn_cvt_pkrtz(W_ih[(1 * HN + g) * 4 + 2] * LOG2E,
                                             W_ih[(1 * HN + g) * 4 + 3] * LOG2E);
    half2v wgp0 = __builtin_amdgcn_cvt_pkrtz(W_ih[(2 * HN + g) * 4 + 0] * 2.0f * LOG2E,
                                             W_ih[(2 * HN + g) * 4 + 1] * 2.0f * LOG2E);
    half2v wgp1 = __builtin_amdgcn_cvt_pkrtz(W_ih[(2 * HN + g) * 4 + 2] * 2.0f * LOG2E,
                                             W_ih[(2 * HN + g) * 4 + 3] * 2.0f * LOG2E);
    half2v wop0 = __builtin_amdgcn_cvt_pkrtz(W_ih[(3 * HN + g) * 4 + 0] * LOG2E,
                                             W_ih[(3 * HN + g) * 4 + 1] * LOG2E);
    half2v wop1 = __builtin_amdgcn_cvt_pkrtz(W_ih[(3 * HN + g) * 4 + 2] * LOG2E,
                                             W_ih[(3 * HN + g) * 4 + 3] * LOG2E);

    const float bias_i = (b_ih[0 * HN + g] + b_hh[0 * HN + g]) * LOG2E;
    const float bias_f = (b_ih[1 * HN + g] + b_hh[1 * HN + g]) * LOG2E;
    const float bias_g = (b_ih[2 * HN + g] + b_hh[2 * HN + g]) * (2.0f * LOG2E);
    const float bias_o = (b_ih[3 * HN + g] + b_hh[3 * HN + g]) * LOG2E;
    const float wfc = W_fc[g];
    const float bfc = b_fc[0];

    const float* xb = x   + (size_t)b * TLEN * 4;
    float*       ob = out + (size_t)b * TLEN;

    float h = 0.0f, c = 0.0f;
    int hp = 0;   // packed h pair {h[j], h[j+32]} per lane (start: h=0)

    // ---- x stage: lane s holds x[t0 + s] (16B coalesced per chunk) ----
    float4 xcur = *(const float4*)(xb + (size_t)g * 4);   // chunk 0

    for (int ci = 0; ci < TLEN / 64; ++ci) {
        const int cn = (ci < TLEN / 64 - 1) ? ci + 1 : ci;
        float4 xnext = *(const float4*)(xb + (size_t)(cn * 64 + g) * 4); // prefetch: 64 steps ahead

        // pack this chunk's x for readlane broadcast: {x0,x1},{x2,x3}
        const int xq0 = __builtin_bit_cast(int, __builtin_amdgcn_cvt_pkrtz(xcur.x, xcur.y));
        const int xq1 = __builtin_bit_cast(int, __builtin_amdgcn_cvt_pkrtz(xcur.z, xcur.w));

#pragma unroll 2
        for (int s = 0; s < 64; ++s) {
            // broadcast x[t] (uniform) from the stage regs: 2 readlanes
            const int xi0 = __builtin_amdgcn_readlane(xq0, s);
            const int xi1 = __builtin_amdgcn_readlane(xq1, s);
            const half2v xh0 = __builtin_bit_cast(half2v, xi0);
            const half2v xh1 = __builtin_bit_cast(half2v, xi1);

            // ---- gate accumulators: 2 chains per gate (17-deep each) ----
            float ai0 = __builtin_amdgcn_fdot2(wip0, xh0, bias_i, false);
            float af0 = __builtin_amdgcn_fdot2(wfp0, xh0, bias_f, false);
            float ag0 = __builtin_amdgcn_fdot2(wgp0, xh0, bias_g, false);
            float ao0 = __builtin_amdgcn_fdot2(wop0, xh0, bias_o, false);
            float ai1 = __builtin_amdgcn_fdot2(wip1, xh1, 0.0f, false);
            float af1 = __builtin_amdgcn_fdot2(wfp1, xh1, 0.0f, false);
            float ag1 = __builtin_amdgcn_fdot2(wgp1, xh1, 0.0f, false);
            float ao1 = __builtin_amdgcn_fdot2(wop1, xh1, 0.0f, false);

            // ---- hh matvec: 32 readlanes x 4 dot2 (pairs {j, j+32}) ----
#define MACA(j) { \
            int hj = __builtin_amdgcn_readlane(hp, j); \
            half2v hh = __builtin_bit_cast(half2v, hj); \
            ai0 = __builtin_amdgcn_fdot2(pi##j, hh, ai0, false); \
            af0 = __builtin_amdgcn_fdot2(pf##j, hh, af0, false); \
            ag0 = __builtin_amdgcn_fdot2(pg##j, hh, ag0, false); \
            ao0 = __builtin_amdgcn_fdot2(po##j, hh, ao0, false); }
#define MACB(j) { \
            int hj = __builtin_amdgcn_readlane(hp, j); \
            half2v hh = __builtin_bit_cast(half2v, hj); \
            ai1 = __builtin_amdgcn_fdot2(pi##j, hh, ai1, false); \
            af1 = __builtin_amdgcn_fdot2(pf##j, hh, af1, false); \
            ag1 = __builtin_amdgcn_fdot2(pg##j, hh, ag1, false); \
            ao1 = __builtin_amdgcn_fdot2(po##j, hh, ao1, false); }
            FOR16A(MACA)
            FOR16B(MACB)
#undef MACA
#undef MACB

            const float ai = ai0 + ai1;
            const float af = af0 + af1;
            const float ag = ag0 + ag1;
            const float ao = ao0 + ao1;

            // ---- activations (pre-scaled): sigmoid/tanh via exp2+rcp ----
            float si = __builtin_amdgcn_rcpf(1.0f + __builtin_amdgcn_exp2f(-ai));
            float sf = __builtin_amdgcn_rcpf(1.0f + __builtin_amdgcn_exp2f(-af));
            float tg = 1.0f - 2.0f * __builtin_amdgcn_rcpf(
                                         1.0f + __builtin_amdgcn_exp2f(ag));
            float so = __builtin_amdgcn_rcpf(1.0f + __builtin_amdgcn_exp2f(-ao));

            c = sf * c + si * tg;
            float th = 1.0f - 2.0f * __builtin_amdgcn_rcpf(
                           1.0f + __builtin_amdgcn_exp2f(c * (2.0f * LOG2E)));
            h = so * th;

            // ---- h half-exchange on the VALU pipe (no DS!) ----
            // v_permlane32_swap_b32 D,S: D[32:63] <-> S[0:31]. Copy h into
            // a DISTINCT register (early-clobber) first, then swap: after,
            // ps[i<32] = h[i+32] (lanes >=32 of ps are don't-care: the
            // readlanes above only touch lanes 0..31).
            int pd = __builtin_bit_cast(int, h);
            int ps;
            asm("v_mov_b32 %1, %0\n\t"
                "v_permlane32_swap_b32 %0, %1"
                : "+v"(pd), "=&v"(ps));
            const float h_hi = __builtin_bit_cast(float, ps);
            hp = __builtin_bit_cast(int, __builtin_amdgcn_cvt_pkrtz(h, h_hi));

            // FC partial into the ring (read back once per 64 steps)
            ring[s][g] = h * wfc;
        }

        // ---- FC: transposed reduce + coalesced 64-wide store ----
        __syncthreads();   // single wave: just orders LDS w->r
        float s0 = 0.f, s1 = 0.f, s2 = 0.f, s3 = 0.f;
#pragma unroll
        for (int k = 0; k < HN; k += 4) {
            s0 += ring[g][k];
            s1 += ring[g][k + 1];
            s2 += ring[g][k + 2];
            s3 += ring[g][k + 3];
        }
        ob[ci * 64 + g] = (s0 + s1) + (s2 + s3) + bfc;

        xcur = xnext;
    }
}

extern "C" void kernel_launch(void* const* d_in, const int* in_sizes, int n_in,
                              void* d_out, int out_size, void* d_ws, size_t ws_size,
                              hipStream_t stream) {
    const float* x    = (const float*)d_in[0];
    const float* W_ih = (const float*)d_in[1];
    const float* W_hh = (const float*)d_in[2];
    const float* b_ih = (const float*)d_in[3];
    const float* b_hh = (const float*)d_in[4];
    const float* W_fc = (const float*)d_in[5];
    const float* b_fc = (const float*)d_in[6];
    float* out = (float*)d_out;

    const int B = in_sizes[0] / (TLEN * 4);   // 1024
    lstm_dot2<<<dim3(B), dim3(64), 0, stream>>>(
        x, W_ih, W_hh, b_ih, b_hh, W_fc, b_fc, out);
}

// Round 3
// 543.871 us; speedup vs baseline: 1.3606x; 1.2012x over previous
//
#include <hip/hip_runtime.h>

#define TLEN  1024
#define HN    64
#define LOG2E 1.4426950408889634f

// clang builtins (__builtin_amdgcn_cvt_pkrtz / fdot2) use __fp16 vectors,
// NOT _Float16 -- R7 failed to compile on exactly that.
typedef __fp16 half2v __attribute__((ext_vector_type(2)));

// One wave (64 lanes) per batch element; 1024 blocks x 64 thr = 1 wave/SIMD
// exactly -> latency-bound. R2 analysis: ~470 cy/step of issue vs 1490
// cy/step measured => ~1000 cy of exposed stalls. Suspects (both in the MAC
// block): (a) v_readlane writes an SGPR that the fdot2 4 cycles later reads
// -> VALU-write-SGPR hazard wait states, paid 32x/step; (b) only 4 acc
// chains rotate inside each 16-group half -> chain links re-issue every 8cy,
// stalling if dot2 latency > 8. This version restructures the MAC block into
// 4x { 8 readlanes hoisted; 32 fdot2 rotating ALL 8 chains }:
//   - hazard distance RL->use >= 16cy (hidden behind the other RLs)
//   - chain-link spacing 16cy (covers VOP3P latency)
//   - <= 8 extra live SGPRs, zero extra instructions, bit-identical math.
// Carried from earlier rounds:
//  * h half-exchange via v_permlane32_swap_b32 (VALU) not __shfl_down (DS).
//    Swap operands MUST be distinct physical VGPRs (R1 failed on coalesced
//    "+v","+v"): v_mov into early-clobber "=&v", then swap.
//  * x staged 64 steps/chunk: one coalesced 16B/lane load per chunk, two
//    v_readlane broadcasts per step; prefetch distance = 64 steps.
//  * FC epilogue outside the inner loop (trip 64 == FC period).
// Weights: lane g owns hidden unit g's 4 gate rows (torch i,f,g,o) as packed
// f16 pairs {w[j], w[j+32]}: 128 half2. v_dot2_f32_f16 = 2 MACs/instr, fp32
// accumulate. log2e pre-folded into weights/biases (2*log2e for tanh gates).

#define FOR16A(X) \
    X(0) X(1) X(2) X(3) X(4) X(5) X(6) X(7) \
    X(8) X(9) X(10) X(11) X(12) X(13) X(14) X(15)
#define FOR16B(X) \
    X(16) X(17) X(18) X(19) X(20) X(21) X(22) X(23) \
    X(24) X(25) X(26) X(27) X(28) X(29) X(30) X(31)
#define FOR32(X) FOR16A(X) FOR16B(X)

__global__ __launch_bounds__(64, 1)
void lstm_dot2(const float* __restrict__ x,      // [B, T, 4]
               const float* __restrict__ W_ih,   // [256, 4]
               const float* __restrict__ W_hh,   // [256, 64]
               const float* __restrict__ b_ih,   // [256]
               const float* __restrict__ b_hh,   // [256]
               const float* __restrict__ W_fc,   // [1, 64]
               const float* __restrict__ b_fc,   // [1]
               float* __restrict__ out)          // [B, T]
{
    const int b = blockIdx.x;
    const int g = threadIdx.x;   // hidden unit 0..63 (also x-stage slot)

    __shared__ float ring[64][65];   // FC partials, stride-65: conflict-free

    const float* wr_i = W_hh + (0 * HN + g) * HN;
    const float* wr_f = W_hh + (1 * HN + g) * HN;
    const float* wr_g = W_hh + (2 * HN + g) * HN;
    const float* wr_o = W_hh + (3 * HN + g) * HN;

    // ---- 128 named half2 weight pairs, pre-scaled, pinned ----
#define DECL(j) half2v pi##j, pf##j, pg##j, po##j;
    FOR32(DECL)
#undef DECL

#define LOADW(j) \
    pi##j = __builtin_amdgcn_cvt_pkrtz(wr_i[j] * LOG2E, wr_i[(j) + 32] * LOG2E); \
    pf##j = __builtin_amdgcn_cvt_pkrtz(wr_f[j] * LOG2E, wr_f[(j) + 32] * LOG2E); \
    pg##j = __builtin_amdgcn_cvt_pkrtz(wr_g[j] * (2.0f * LOG2E), \
                                       wr_g[(j) + 32] * (2.0f * LOG2E)); \
    po##j = __builtin_amdgcn_cvt_pkrtz(wr_o[j] * LOG2E, wr_o[(j) + 32] * LOG2E); \
    asm volatile("" : "+v"(pi##j), "+v"(pf##j), "+v"(pg##j), "+v"(po##j));
    FOR32(LOADW)
#undef LOADW

    // x-weights as f16 pairs (pre-scaled): 2 half2 per gate
    half2v wip0 = __builtin_amdgcn_cvt_pkrtz(W_ih[(0 * HN + g) * 4 + 0] * LOG2E,
                                             W_ih[(0 * HN + g) * 4 + 1] * LOG2E);
    half2v wip1 = __builtin_amdgcn_cvt_pkrtz(W_ih[(0 * HN + g) * 4 + 2] * LOG2E,
                                             W_ih[(0 * HN + g) * 4 + 3] * LOG2E);
    half2v wfp0 = __builtin_amdgcn_cvt_pkrtz(W_ih[(1 * HN + g) * 4 + 0] * LOG2E,
                                             W_ih[(1 * HN + g) * 4 + 1] * LOG2E);
    half2v wfp1 = __builtin_amdgcn_cvt_pkrtz(W_ih[(1 * HN + g) * 4 + 2] * LOG2E,
                                             W_ih[(1 * HN + g) * 4 + 3] * LOG2E);
    half2v wgp0 = __builtin_amdgcn_cvt_pkrtz(W_ih[(2 * HN + g) * 4 + 0] * 2.0f * LOG2E,
                                             W_ih[(2 * HN + g) * 4 + 1] * 2.0f * LOG2E);
    half2v wgp1 = __builtin_amdgcn_cvt_pkrtz(W_ih[(2 * HN + g) * 4 + 2] * 2.0f * LOG2E,
                                             W_ih[(2 * HN + g) * 4 + 3] * 2.0f * LOG2E);
    half2v wop0 = __builtin_amdgcn_cvt_pkrtz(W_ih[(3 * HN + g) * 4 + 0] * LOG2E,
                                             W_ih[(3 * HN + g) * 4 + 1] * LOG2E);
    half2v wop1 = __builtin_amdgcn_cvt_pkrtz(W_ih[(3 * HN + g) * 4 + 2] * LOG2E,
                                             W_ih[(3 * HN + g) * 4 + 3] * LOG2E);

    const float bias_i = (b_ih[0 * HN + g] + b_hh[0 * HN + g]) * LOG2E;
    const float bias_f = (b_ih[1 * HN + g] + b_hh[1 * HN + g]) * LOG2E;
    const float bias_g = (b_ih[2 * HN + g] + b_hh[2 * HN + g]) * (2.0f * LOG2E);
    const float bias_o = (b_ih[3 * HN + g] + b_hh[3 * HN + g]) * LOG2E;
    const float wfc = W_fc[g];
    const float bfc = b_fc[0];

    const float* xb = x   + (size_t)b * TLEN * 4;
    float*       ob = out + (size_t)b * TLEN;

    float h = 0.0f, c = 0.0f;
    int hp = 0;   // packed h pair {h[j], h[j+32]} per lane (start: h=0)

    // ---- x stage: lane s holds x[t0 + s] (16B coalesced per chunk) ----
    float4 xcur = *(const float4*)(xb + (size_t)g * 4);   // chunk 0

    for (int ci = 0; ci < TLEN / 64; ++ci) {
        const int cn = (ci < TLEN / 64 - 1) ? ci + 1 : ci;
        float4 xnext = *(const float4*)(xb + (size_t)(cn * 64 + g) * 4); // prefetch: 64 steps ahead

        // pack this chunk's x for readlane broadcast: {x0,x1},{x2,x3}
        const int xq0 = __builtin_bit_cast(int, __builtin_amdgcn_cvt_pkrtz(xcur.x, xcur.y));
        const int xq1 = __builtin_bit_cast(int, __builtin_amdgcn_cvt_pkrtz(xcur.z, xcur.w));

#pragma unroll 2
        for (int s = 0; s < 64; ++s) {
            // broadcast x[t] (uniform) from the stage regs: 2 readlanes
            const int xi0 = __builtin_amdgcn_readlane(xq0, s);
            const int xi1 = __builtin_amdgcn_readlane(xq1, s);
            const half2v xh0 = __builtin_bit_cast(half2v, xi0);
            const half2v xh1 = __builtin_bit_cast(half2v, xi1);

            // ---- gate accumulators: 2 chains per gate (17-deep each) ----
            float ai0 = __builtin_amdgcn_fdot2(wip0, xh0, bias_i, false);
            float af0 = __builtin_amdgcn_fdot2(wfp0, xh0, bias_f, false);
            float ag0 = __builtin_amdgcn_fdot2(wgp0, xh0, bias_g, false);
            float ao0 = __builtin_amdgcn_fdot2(wop0, xh0, bias_o, false);
            float ai1 = __builtin_amdgcn_fdot2(wip1, xh1, 0.0f, false);
            float af1 = __builtin_amdgcn_fdot2(wfp1, xh1, 0.0f, false);
            float ag1 = __builtin_amdgcn_fdot2(wgp1, xh1, 0.0f, false);
            float ao1 = __builtin_amdgcn_fdot2(wop1, xh1, 0.0f, false);

            // ---- hh matvec: 4 x { 8 hoisted readlanes; 32 fdot2 rotating
            //      all 8 chains }. RL->use distance >= 16cy (hazard hidden),
            //      chain-link spacing 16cy (covers dot2 latency). Same
            //      accumulation order per chain as before: bit-identical.
#define BLOCK(a0,a1,a2,a3,b0,b1,b2,b3) { \
            const int qA0 = __builtin_amdgcn_readlane(hp, a0); \
            const int qA1 = __builtin_amdgcn_readlane(hp, a1); \
            const int qA2 = __builtin_amdgcn_readlane(hp, a2); \
            const int qA3 = __builtin_amdgcn_readlane(hp, a3); \
            const int qB0 = __builtin_amdgcn_readlane(hp, b0); \
            const int qB1 = __builtin_amdgcn_readlane(hp, b1); \
            const int qB2 = __builtin_amdgcn_readlane(hp, b2); \
            const int qB3 = __builtin_amdgcn_readlane(hp, b3); \
            const half2v hA0 = __builtin_bit_cast(half2v, qA0); \
            const half2v hA1 = __builtin_bit_cast(half2v, qA1); \
            const half2v hA2 = __builtin_bit_cast(half2v, qA2); \
            const half2v hA3 = __builtin_bit_cast(half2v, qA3); \
            const half2v hB0 = __builtin_bit_cast(half2v, qB0); \
            const half2v hB1 = __builtin_bit_cast(half2v, qB1); \
            const half2v hB2 = __builtin_bit_cast(half2v, qB2); \
            const half2v hB3 = __builtin_bit_cast(half2v, qB3); \
            ai0 = __builtin_amdgcn_fdot2(pi##a0, hA0, ai0, false); \
            ai1 = __builtin_amdgcn_fdot2(pi##b0, hB0, ai1, false); \
            af0 = __builtin_amdgcn_fdot2(pf##a0, hA0, af0, false); \
            af1 = __builtin_amdgcn_fdot2(pf##b0, hB0, af1, false); \
            ag0 = __builtin_amdgcn_fdot2(pg##a0, hA0, ag0, false); \
            ag1 = __builtin_amdgcn_fdot2(pg##b0, hB0, ag1, false); \
            ao0 = __builtin_amdgcn_fdot2(po##a0, hA0, ao0, false); \
            ao1 = __builtin_amdgcn_fdot2(po##b0, hB0, ao1, false); \
            ai0 = __builtin_amdgcn_fdot2(pi##a1, hA1, ai0, false); \
            ai1 = __builtin_amdgcn_fdot2(pi##b1, hB1, ai1, false); \
            af0 = __builtin_amdgcn_fdot2(pf##a1, hA1, af0, false); \
            af1 = __builtin_amdgcn_fdot2(pf##b1, hB1, af1, false); \
            ag0 = __builtin_amdgcn_fdot2(pg##a1, hA1, ag0, false); \
            ag1 = __builtin_amdgcn_fdot2(pg##b1, hB1, ag1, false); \
            ao0 = __builtin_amdgcn_fdot2(po##a1, hA1, ao0, false); \
            ao1 = __builtin_amdgcn_fdot2(po##b1, hB1, ao1, false); \
            ai0 = __builtin_amdgcn_fdot2(pi##a2, hA2, ai0, false); \
            ai1 = __builtin_amdgcn_fdot2(pi##b2, hB2, ai1, false); \
            af0 = __builtin_amdgcn_fdot2(pf##a2, hA2, af0, false); \
            af1 = __builtin_amdgcn_fdot2(pf##b2, hB2, af1, false); \
            ag0 = __builtin_amdgcn_fdot2(pg##a2, hA2, ag0, false); \
            ag1 = __builtin_amdgcn_fdot2(pg##b2, hB2, ag1, false); \
            ao0 = __builtin_amdgcn_fdot2(po##a2, hA2, ao0, false); \
            ao1 = __builtin_amdgcn_fdot2(po##b2, hB2, ao1, false); \
            ai0 = __builtin_amdgcn_fdot2(pi##a3, hA3, ai0, false); \
            ai1 = __builtin_amdgcn_fdot2(pi##b3, hB3, ai1, false); \
            af0 = __builtin_amdgcn_fdot2(pf##a3, hA3, af0, false); \
            af1 = __builtin_amdgcn_fdot2(pf##b3, hB3, af1, false); \
            ag0 = __builtin_amdgcn_fdot2(pg##a3, hA3, ag0, false); \
            ag1 = __builtin_amdgcn_fdot2(pg##b3, hB3, ag1, false); \
            ao0 = __builtin_amdgcn_fdot2(po##a3, hA3, ao0, false); \
            ao1 = __builtin_amdgcn_fdot2(po##b3, hB3, ao1, false); }

            BLOCK(0, 1, 2, 3, 16, 17, 18, 19)
            BLOCK(4, 5, 6, 7, 20, 21, 22, 23)
            BLOCK(8, 9, 10, 11, 24, 25, 26, 27)
            BLOCK(12, 13, 14, 15, 28, 29, 30, 31)
#undef BLOCK

            const float ai = ai0 + ai1;
            const float af = af0 + af1;
            const float ag = ag0 + ag1;
            const float ao = ao0 + ao1;

            // ---- activations (pre-scaled): sigmoid/tanh via exp2+rcp ----
            float si = __builtin_amdgcn_rcpf(1.0f + __builtin_amdgcn_exp2f(-ai));
            float sf = __builtin_amdgcn_rcpf(1.0f + __builtin_amdgcn_exp2f(-af));
            float tg = 1.0f - 2.0f * __builtin_amdgcn_rcpf(
                                         1.0f + __builtin_amdgcn_exp2f(ag));
            float so = __builtin_amdgcn_rcpf(1.0f + __builtin_amdgcn_exp2f(-ao));

            c = sf * c + si * tg;
            float th = 1.0f - 2.0f * __builtin_amdgcn_rcpf(
                           1.0f + __builtin_amdgcn_exp2f(c * (2.0f * LOG2E)));
            h = so * th;

            // ---- h half-exchange on the VALU pipe (no DS!) ----
            // v_permlane32_swap_b32 D,S: D[32:63] <-> S[0:31]. Copy h into
            // a DISTINCT register (early-clobber) first, then swap: after,
            // ps[i<32] = h[i+32] (lanes >=32 of ps are don't-care: the
            // readlanes above only touch lanes 0..31).
            int pd = __builtin_bit_cast(int, h);
            int ps;
            asm("v_mov_b32 %1, %0\n\t"
                "v_permlane32_swap_b32 %0, %1"
                : "+v"(pd), "=&v"(ps));
            const float h_hi = __builtin_bit_cast(float, ps);
            hp = __builtin_bit_cast(int, __builtin_amdgcn_cvt_pkrtz(h, h_hi));

            // FC partial into the ring (read back once per 64 steps)
            ring[s][g] = h * wfc;
        }

        // ---- FC: transposed reduce + coalesced 64-wide store ----
        __syncthreads();   // single wave: just orders LDS w->r
        float s0 = 0.f, s1 = 0.f, s2 = 0.f, s3 = 0.f;
#pragma unroll
        for (int k = 0; k < HN; k += 4) {
            s0 += ring[g][k];
            s1 += ring[g][k + 1];
            s2 += ring[g][k + 2];
            s3 += ring[g][k + 3];
        }
        ob[ci * 64 + g] = (s0 + s1) + (s2 + s3) + bfc;

        xcur = xnext;
    }
}

extern "C" void kernel_launch(void* const* d_in, const int* in_sizes, int n_in,
                              void* d_out, int out_size, void* d_ws, size_t ws_size,
                              hipStream_t stream) {
    const float* x    = (const float*)d_in[0];
    const float* W_ih = (const float*)d_in[1];
    const float* W_hh = (const float*)d_in[2];
    const float* b_ih = (const float*)d_in[3];
    const float* b_hh = (const float*)d_in[4];
    const float* W_fc = (const float*)d_in[5];
    const float* b_fc = (const float*)d_in[6];
    float* out = (float*)d_out;

    const int B = in_sizes[0] / (TLEN * 4);   // 1024
    lstm_dot2<<<dim3(B), dim3(64), 0, stream>>>(
        x, W_ih, W_hh, b_ih, b_hh, W_fc, b_fc, out);
}